// Round 4
// baseline (158.032 us; speedup 1.0000x reference)
//
#include <hip/hip_runtime.h>
#include <math.h>

// N=4, R=16384, K=96. Output: rgb [65536*3] | depth [65536] | weights [65536*95]
#define NRAYS     65536
#define RGB_OFF   0
#define DEPTH_OFF (NRAYS * 3)
#define W_OFF     (NRAYS * 4)

#define RPB 16               // rays per block (256 threads, 4 waves, 4 rays/wave)
// input staging layout (floats); pads absorb lane-15 overreads
#define SHD_OFF 0            // 16*96 = 1536 used, pad to 1540
#define SHS_OFF 1540
#define SHR_OFF 3080         // 16*288 = 4608 used, pad to 4616
#define SH_TOTAL 7696        // 30784 B -> 5 blocks/CU (20 waves)

typedef float v4f __attribute__((ext_vector_type(4)));

#define DPPF(oldv, x, ctrl)                                                    \
    __int_as_float(__builtin_amdgcn_update_dpp(                                \
        __float_as_int(oldv), __float_as_int(x), (ctrl), 0xF, 0xF, false))

#define WAITVM(N) asm volatile("s_waitcnt vmcnt(" #N ")" ::: "memory")
#define LGKM0     asm volatile("s_waitcnt lgkmcnt(0)" ::: "memory")
// compiler-level fence: pins intrinsic memory-op order at IR (asm memory
// clobber) AND MachineScheduler (sched_barrier(0)) level. No runtime cost.
#define SCHED_PIN()                                                            \
    do { asm volatile("" ::: "memory");                                        \
         __builtin_amdgcn_sched_barrier(0); } while (0)

// 1-alpha = exp(-delta*softplus(x)) via HW transcendentals. absmax 7.8e-3 ok.
__device__ __forceinline__ float one_minus_alpha(float x, float delta) {
    const float L2E = 1.44269504088896340736f;
    float xl = x * L2E;
    float l2 = (x > 20.0f) ? xl
                           : __builtin_amdgcn_logf(1.0f + __builtin_amdgcn_exp2f(xl));
    return __builtin_amdgcn_exp2f(-delta * l2);
}

// R12: async global->LDS DMA with aux=0 (NORMAL cache allocate).
// R8-R11 used aux=2 (SLC/NT no-allocate): correct for "read once" within a
// launch, but across the bench's repeated launches it meant input lines
// evicted by the harness's 302MB poison fills were never repopulated into
// L3 -> steady-state HBM re-misses (~8.7 TB/s effective read, mixed model
// says ~half the reads went to HBM). aux=0 lets our own reads re-allocate
// the inputs in L3 each launch. Single-variable A/B vs R11.
__device__ __forceinline__ void gload_lds16(const float* g, float* l) {
    __builtin_amdgcn_global_load_lds(
        (const __attribute__((address_space(1))) void*)g,
        (__attribute__((address_space(3))) void*)l, 16, 0, 0);
}
__device__ __forceinline__ void gload_lds4(const float* g, float* l) {
    __builtin_amdgcn_global_load_lds(
        (const __attribute__((address_space(1))) void*)g,
        (__attribute__((address_space(3))) void*)l, 4, 0, 0);
}

// ---------------------------------------------------------------------------
// Structure identical to R11 (wave-decoupled, zero barriers, 20 waves/CU):
//  - each wave DMAs only ITS OWN 4 rays' data, all chunks full-wave
//    (16B/lane x1 + 4B/lane x2 per 384-float slice; rgb = x4 + x2).
//  - issue order d,s | rgb PINNED (asm clobber + sched_barrier) so the split
//    wait vmcnt(6) provably means d+s landed; pass 1 transcendentals run
//    while rgb chunks are still in flight.
//  - outputs staged into the wave's OWN dead input slices; per-wave NT
//    stores (95+3+1 dwordx4). NT on stores kept: output must not evict
//    inputs from L3.
// ---------------------------------------------------------------------------
__global__ __launch_bounds__(256) void integrate_kernel(
    const float* __restrict__ rgbs,     // [NRAYS, 96, 3]
    const float* __restrict__ sigmas,   // [NRAYS, 96]
    const float* __restrict__ depths,   // [NRAYS, 96]
    float* __restrict__ out)
{
    __shared__ float sh[SH_TOTAL];

    const int t   = threadIdx.x;
    const int w   = t >> 6;
    const int l64 = t & 63;
    // XCD-contiguous swizzle: 4096 blocks = 8 XCDs x 512 contiguous
    const int blk = ((blockIdx.x & 7) << 9) | (blockIdx.x >> 3);

    // ---- per-wave async staging of its own 4 rays (7680 B) ----
    {
        const float* gd = depths + (size_t)blk * (RPB * 96)  + w * 384;
        const float* gs = sigmas + (size_t)blk * (RPB * 96)  + w * 384;
        const float* gr = rgbs   + (size_t)blk * (RPB * 288) + w * 1152;
        float* dd  = sh + SHD_OFF + w * 384;
        float* dsg = sh + SHS_OFF + w * 384;
        float* dr  = sh + SHR_OFF + w * 1152;

        // group 1: d then s (6 full-wave issues)
        gload_lds16(gd + l64 * 4, dd + l64 * 4);              // d[0,256)
        gload_lds4 (gd + 256 + l64, dd + 256 + l64);          // d[256,320)
        gload_lds4 (gd + 320 + l64, dd + 320 + l64);          // d[320,384)
        gload_lds16(gs + l64 * 4, dsg + l64 * 4);             // s[0,256)
        gload_lds4 (gs + 256 + l64, dsg + 256 + l64);
        gload_lds4 (gs + 320 + l64, dsg + 320 + l64);

        SCHED_PIN();   // group 1 strictly older than group 2 in vmcnt order

        // group 2: rgb (6 full-wave issues)
#pragma unroll
        for (int c = 0; c < 4; ++c)
            gload_lds16(gr + c * 256 + l64 * 4, dr + c * 256 + l64 * 4);
        gload_lds4(gr + 1024 + l64, dr + 1024 + l64);
        gload_lds4(gr + 1088 + l64, dr + 1088 + l64);

        SCHED_PIN();   // nothing from either group sinks below the waits
    }

    const int rb_  = t >> 4;            // ray within block
    const int rloc = rb_ & 3;           // ray within wave
    const int l    = t & 15;            // segment within ray
    const bool full = (l < 15);

    // ---- wait for group 1 only (rgb's 6 issues still in flight) ----
    WAITVM(6);

    const float* db = sh + SHD_OFF + rb_ * 96 + 6 * l;
    const float* sp = sh + SHS_OFF + rb_ * 96 + 6 * l;

    float2 e0 = *(const float2*)(db);
    float2 e1 = *(const float2*)(db + 2);
    float2 e2 = *(const float2*)(db + 4);
    float2 e3 = *(const float2*)(db + 6);
    float2 f0 = *(const float2*)(sp);
    float2 f1 = *(const float2*)(sp + 2);
    float2 f2v = *(const float2*)(sp + 4);
    float2 f3 = *(const float2*)(sp + 6);
    LGKM0;

    const float D[7] = {e0.x, e0.y, e1.x, e1.y, e2.x, e2.y, e3.x};
    const float S[7] = {f0.x, f0.y, f1.x, f1.y, f2v.x, f2v.y, f3.x};

    // ---- pass 1: alpha/transmittance (transcendental-heavy) + Sw, Sd ----
    float u[6];
    float Tloc = 1.0f;
    float Sw = 0.f, Sd = 0.f;

#define DO_A(I)                                                       \
    { float delta = D[(I)+1] - D[I];                                  \
      float x = 0.5f * (S[I] + S[(I)+1]) - 1.0f;                      \
      float e = one_minus_alpha(x, delta);                            \
      float uu = (1.0f - e) * Tloc;                                   \
      Tloc *= e + 1e-10f;                                             \
      u[I] = uu;                                                      \
      Sw  += uu;                                                      \
      Sd  += uu * (0.5f * (D[I] + D[(I)+1])); }

    DO_A(0) DO_A(1) DO_A(2) DO_A(3) DO_A(4)
    if (full) { DO_A(5) } else { u[5] = 0.f; }
#undef DO_A

    // ---- exclusive prefix product of segment transmittances (DPP row scan)
    float incl = Tloc;
    incl *= DPPF(1.0f, incl, 0x111);
    incl *= DPPF(1.0f, incl, 0x112);
    incl *= DPPF(1.0f, incl, 0x114);
    incl *= DPPF(1.0f, incl, 0x118);
    float Tin = DPPF(1.0f, incl, 0x111);   // exclusive; lane0 = 1.0

    Sw *= Tin; Sd *= Tin;

#define RED(v)                         \
    v += DPPF(0.f, v, 0x111);          \
    v += DPPF(0.f, v, 0x112);          \
    v += DPPF(0.f, v, 0x114);          \
    v += DPPF(0.f, v, 0x118);
    RED(Sw) RED(Sd)

    float lo0 = 0.5f * (D[0] + D[1]);
    float lo  = DPPF(0.f, lo0, 0x11F);     // lane0 -> lane15

    // ---- rgb has had pass-1 latency to land; finish the color pass ----
    WAITVM(0);
    const float* rp = sh + SHR_OFF + rb_ * 288 + 18 * l;
    float2 c0 = *(const float2*)(rp);
    float2 c1 = *(const float2*)(rp + 2);
    float2 c2 = *(const float2*)(rp + 4);
    float2 c3 = *(const float2*)(rp + 6);
    float2 c4 = *(const float2*)(rp + 8);
    float2 c5 = *(const float2*)(rp + 10);
    float2 c6 = *(const float2*)(rp + 12);
    float2 c7 = *(const float2*)(rp + 14);
    float2 c8 = *(const float2*)(rp + 16);
    float2 c9 = *(const float2*)(rp + 18);
    float  r20 = rp[20];
    LGKM0;

    const float R[7] = {c0.x, c1.y, c3.x, c4.y, c6.x, c7.y, c9.x};
    const float G[7] = {c0.y, c2.x, c3.y, c5.x, c6.y, c8.x, c9.y};
    const float B[7] = {c1.x, c2.y, c4.x, c5.y, c7.x, c8.y, r20};

    float Sr = 0.f, Sg = 0.f, Sbv = 0.f;
#define DO_B(I)                                                       \
    { Sr  += u[I] * (0.5f * (R[I] + R[(I)+1]));                       \
      Sg  += u[I] * (0.5f * (G[I] + G[(I)+1]));                       \
      Sbv += u[I] * (0.5f * (B[I] + B[(I)+1])); }
    DO_B(0) DO_B(1) DO_B(2) DO_B(3) DO_B(4)
    if (full) { DO_B(5) }   // guard: R[6]/G[6]/B[6] are garbage on lane 15
#undef DO_B

    Sr *= Tin; Sg *= Tin; Sbv *= Tin;
    RED(Sr) RED(Sg) RED(Sbv)
#undef RED

    // ---- stage outputs into this wave's OWN dead input slices ----
    // weights (380 floats) -> its D slice (384 floats)
    {
        float* wst = sh + SHD_OFF + w * 384 + rloc * 95 + 6 * l;
        float2* wst2 = (float2*)wst;
        wst2[0] = float2{Tin * u[0], Tin * u[1]};
        wst2[1] = float2{Tin * u[2], Tin * u[3]};
        if (full) wst2[2] = float2{Tin * u[4], Tin * u[5]};
        else      wst[4]  = Tin * u[4];
    }
    // rgb (12 floats) + depth (4 floats) -> its S slice
    if (l == 15) {
        float* cst = sh + SHS_OFF + w * 384;
        cst[rloc * 3 + 0] = 2.f * Sr  - 1.f;
        cst[rloc * 3 + 1] = 2.f * Sg  - 1.f;
        cst[rloc * 3 + 2] = 2.f * Sbv - 1.f;
        float dv = Sd / Sw;                    // normalize_depth
        float hi = 0.5f * (D[4] + D[5]);       // 0.5*(d[94]+d[95]) on lane 15
        dv = fmaxf(fminf(dv, hi), lo);         // NaN -> hi (ref: nan->inf->clip)
        cst[12 + rloc] = dv;
    }
    LGKM0;   // wave-local ds_writes visible to wave-local readback

    // ---- per-wave cooperative NT stores (all spans 16B-aligned) ----
    {
        // weights: 380 floats = 95 dwordx4 per wave
        const v4f* src = (const v4f*)(sh + SHD_OFF + w * 384);
        v4f* dst = (v4f*)(out + W_OFF + ((size_t)blk * RPB + 4 * w) * 95);
        __builtin_nontemporal_store(src[l64], dst + l64);
        if (l64 < 31) __builtin_nontemporal_store(src[64 + l64], dst + 64 + l64);
    }
    if (l64 < 3) {   // rgb: 12 floats = 3 dwordx4
        __builtin_nontemporal_store(
            ((const v4f*)(sh + SHS_OFF + w * 384))[l64],
            (v4f*)(out + RGB_OFF + ((size_t)blk * RPB + 4 * w) * 3) + l64);
    }
    if (l64 == 3) {  // depth: 4 floats = 1 dwordx4
        __builtin_nontemporal_store(
            ((const v4f*)(sh + SHS_OFF + w * 384 + 12))[0],
            (v4f*)(out + DEPTH_OFF + (size_t)blk * RPB + 4 * w));
    }
}

extern "C" void kernel_launch(void* const* d_in, const int* in_sizes, int n_in,
                              void* d_out, int out_size, void* d_ws, size_t ws_size,
                              hipStream_t stream) {
    const float* rgbs   = (const float*)d_in[0];
    const float* sigmas = (const float*)d_in[1];
    const float* depths = (const float*)d_in[2];
    float* out = (float*)d_out;

    // 16 rays per 256-thread block -> 4096 blocks, 5 blocks/CU resident
    integrate_kernel<<<NRAYS / RPB, 256, 0, stream>>>(rgbs, sigmas, depths, out);
}

// Round 5
// 148.696 us; speedup vs baseline: 1.0628x; 1.0628x over previous
//
#include <hip/hip_runtime.h>
#include <math.h>

// N=4, R=16384, K=96. Output: rgb [65536*3] | depth [65536] | weights [65536*95]
#define NRAYS     65536
#define RGB_OFF   0
#define DEPTH_OFF (NRAYS * 3)
#define W_OFF     (NRAYS * 4)

#define RPB 16               // rays per block (256 threads, 4 waves, 4 rays/wave)
// input staging layout (floats); pads absorb lane-15 overreads
#define SHD_OFF 0            // 16*96 = 1536 used, pad to 1540
#define SHS_OFF 1540
#define SHR_OFF 3080         // 16*288 = 4608 used, pad to 4616
#define SH_TOTAL 7696        // 30784 B -> 5 blocks/CU (20 waves)

typedef float v4f __attribute__((ext_vector_type(4)));

#define DPPF(oldv, x, ctrl)                                                    \
    __int_as_float(__builtin_amdgcn_update_dpp(                                \
        __float_as_int(oldv), __float_as_int(x), (ctrl), 0xF, 0xF, false))

#define WAITVM(N) asm volatile("s_waitcnt vmcnt(" #N ")" ::: "memory")
#define LGKM0     asm volatile("s_waitcnt lgkmcnt(0)" ::: "memory")
// compiler-level fence: pins intrinsic memory-op order at IR (asm memory
// clobber) AND MachineScheduler (sched_barrier(0)) level. No runtime cost.
#define SCHED_PIN()                                                            \
    do { asm volatile("" ::: "memory");                                        \
         __builtin_amdgcn_sched_barrier(0); } while (0)

// 1-alpha = exp(-delta*softplus(x)) via HW transcendentals. absmax 7.8e-3 ok.
__device__ __forceinline__ float one_minus_alpha(float x, float delta) {
    const float L2E = 1.44269504088896340736f;
    float xl = x * L2E;
    float l2 = (x > 20.0f) ? xl
                           : __builtin_amdgcn_logf(1.0f + __builtin_amdgcn_exp2f(xl));
    return __builtin_amdgcn_exp2f(-delta * l2);
}

// async global->LDS DMA, aux=2 -> NT (streaming) on input reads.
// A/B-verified across R11 (aux=2, 148.9us) vs R12 (aux=0, 158.0us): the NT
// hint is worth ~9us/iter. Mechanism: inputs are use-once per launch and the
// harness's 3x302MB fills sweep L3 every iteration anyway, so allocate-on-
// miss only thrashes the 4MB/XCD L2 (15.7MB use-once input per XCD).
__device__ __forceinline__ void gload_lds16(const float* g, float* l) {
    __builtin_amdgcn_global_load_lds(
        (const __attribute__((address_space(1))) void*)g,
        (__attribute__((address_space(3))) void*)l, 16, 0, 2);
}
__device__ __forceinline__ void gload_lds4(const float* g, float* l) {
    __builtin_amdgcn_global_load_lds(
        (const __attribute__((address_space(1))) void*)g,
        (__attribute__((address_space(3))) void*)l, 4, 0, 2);
}

// ---------------------------------------------------------------------------
// R13 = R11 exactly (best measured: 148.88us total, kernel ~14.5us = 90% of
// the mixed HBM roofline given measured FETCH=61.5MB + WRITE=26.2MB).
//  - wave-decoupled, zero barriers, 20 waves/CU; each wave DMAs only ITS OWN
//    4 rays' data, all chunks full-wave (no exec-masked DMA — R10 failure).
//  - issue order d,s | rgb PINNED so the split wait vmcnt(6) provably means
//    d+s landed; pass-1 transcendentals run while rgb chunks are in flight.
//  - outputs staged into the wave's OWN dead input slices; per-wave NT
//    stores (95+3+1 dwordx4).
// Schedule-invariance evidence: R8 (3-barrier convoy), R9 (persistent dbuf,
// 8 waves/CU), R11 (zero-barrier) all ~14.5us -> delivery-bound.
// ---------------------------------------------------------------------------
__global__ __launch_bounds__(256) void integrate_kernel(
    const float* __restrict__ rgbs,     // [NRAYS, 96, 3]
    const float* __restrict__ sigmas,   // [NRAYS, 96]
    const float* __restrict__ depths,   // [NRAYS, 96]
    float* __restrict__ out)
{
    __shared__ float sh[SH_TOTAL];

    const int t   = threadIdx.x;
    const int w   = t >> 6;
    const int l64 = t & 63;
    // XCD-contiguous swizzle: 4096 blocks = 8 XCDs x 512 contiguous
    const int blk = ((blockIdx.x & 7) << 9) | (blockIdx.x >> 3);

    // ---- per-wave async NT staging of its own 4 rays (7680 B) ----
    {
        const float* gd = depths + (size_t)blk * (RPB * 96)  + w * 384;
        const float* gs = sigmas + (size_t)blk * (RPB * 96)  + w * 384;
        const float* gr = rgbs   + (size_t)blk * (RPB * 288) + w * 1152;
        float* dd  = sh + SHD_OFF + w * 384;
        float* dsg = sh + SHS_OFF + w * 384;
        float* dr  = sh + SHR_OFF + w * 1152;

        // group 1: d then s (6 full-wave issues)
        gload_lds16(gd + l64 * 4, dd + l64 * 4);              // d[0,256)
        gload_lds4 (gd + 256 + l64, dd + 256 + l64);          // d[256,320)
        gload_lds4 (gd + 320 + l64, dd + 320 + l64);          // d[320,384)
        gload_lds16(gs + l64 * 4, dsg + l64 * 4);             // s[0,256)
        gload_lds4 (gs + 256 + l64, dsg + 256 + l64);
        gload_lds4 (gs + 320 + l64, dsg + 320 + l64);

        SCHED_PIN();   // group 1 strictly older than group 2 in vmcnt order

        // group 2: rgb (6 full-wave issues)
#pragma unroll
        for (int c = 0; c < 4; ++c)
            gload_lds16(gr + c * 256 + l64 * 4, dr + c * 256 + l64 * 4);
        gload_lds4(gr + 1024 + l64, dr + 1024 + l64);
        gload_lds4(gr + 1088 + l64, dr + 1088 + l64);

        SCHED_PIN();   // nothing from either group sinks below the waits
    }

    const int rb_  = t >> 4;            // ray within block
    const int rloc = rb_ & 3;           // ray within wave
    const int l    = t & 15;            // segment within ray
    const bool full = (l < 15);

    // ---- wait for group 1 only (rgb's 6 issues still in flight) ----
    WAITVM(6);

    const float* db = sh + SHD_OFF + rb_ * 96 + 6 * l;
    const float* sp = sh + SHS_OFF + rb_ * 96 + 6 * l;

    float2 e0 = *(const float2*)(db);
    float2 e1 = *(const float2*)(db + 2);
    float2 e2 = *(const float2*)(db + 4);
    float2 e3 = *(const float2*)(db + 6);
    float2 f0 = *(const float2*)(sp);
    float2 f1 = *(const float2*)(sp + 2);
    float2 f2v = *(const float2*)(sp + 4);
    float2 f3 = *(const float2*)(sp + 6);
    LGKM0;

    const float D[7] = {e0.x, e0.y, e1.x, e1.y, e2.x, e2.y, e3.x};
    const float S[7] = {f0.x, f0.y, f1.x, f1.y, f2v.x, f2v.y, f3.x};

    // ---- pass 1: alpha/transmittance (transcendental-heavy) + Sw, Sd ----
    float u[6];
    float Tloc = 1.0f;
    float Sw = 0.f, Sd = 0.f;

#define DO_A(I)                                                       \
    { float delta = D[(I)+1] - D[I];                                  \
      float x = 0.5f * (S[I] + S[(I)+1]) - 1.0f;                      \
      float e = one_minus_alpha(x, delta);                            \
      float uu = (1.0f - e) * Tloc;                                   \
      Tloc *= e + 1e-10f;                                             \
      u[I] = uu;                                                      \
      Sw  += uu;                                                      \
      Sd  += uu * (0.5f * (D[I] + D[(I)+1])); }

    DO_A(0) DO_A(1) DO_A(2) DO_A(3) DO_A(4)
    if (full) { DO_A(5) } else { u[5] = 0.f; }
#undef DO_A

    // ---- exclusive prefix product of segment transmittances (DPP row scan)
    float incl = Tloc;
    incl *= DPPF(1.0f, incl, 0x111);
    incl *= DPPF(1.0f, incl, 0x112);
    incl *= DPPF(1.0f, incl, 0x114);
    incl *= DPPF(1.0f, incl, 0x118);
    float Tin = DPPF(1.0f, incl, 0x111);   // exclusive; lane0 = 1.0

    Sw *= Tin; Sd *= Tin;

#define RED(v)                         \
    v += DPPF(0.f, v, 0x111);          \
    v += DPPF(0.f, v, 0x112);          \
    v += DPPF(0.f, v, 0x114);          \
    v += DPPF(0.f, v, 0x118);
    RED(Sw) RED(Sd)

    float lo0 = 0.5f * (D[0] + D[1]);
    float lo  = DPPF(0.f, lo0, 0x11F);     // lane0 -> lane15

    // ---- rgb has had pass-1 latency to land; finish the color pass ----
    WAITVM(0);
    const float* rp = sh + SHR_OFF + rb_ * 288 + 18 * l;
    float2 c0 = *(const float2*)(rp);
    float2 c1 = *(const float2*)(rp + 2);
    float2 c2 = *(const float2*)(rp + 4);
    float2 c3 = *(const float2*)(rp + 6);
    float2 c4 = *(const float2*)(rp + 8);
    float2 c5 = *(const float2*)(rp + 10);
    float2 c6 = *(const float2*)(rp + 12);
    float2 c7 = *(const float2*)(rp + 14);
    float2 c8 = *(const float2*)(rp + 16);
    float2 c9 = *(const float2*)(rp + 18);
    float  r20 = rp[20];
    LGKM0;

    const float R[7] = {c0.x, c1.y, c3.x, c4.y, c6.x, c7.y, c9.x};
    const float G[7] = {c0.y, c2.x, c3.y, c5.x, c6.y, c8.x, c9.y};
    const float B[7] = {c1.x, c2.y, c4.x, c5.y, c7.x, c8.y, r20};

    float Sr = 0.f, Sg = 0.f, Sbv = 0.f;
#define DO_B(I)                                                       \
    { Sr  += u[I] * (0.5f * (R[I] + R[(I)+1]));                       \
      Sg  += u[I] * (0.5f * (G[I] + G[(I)+1]));                       \
      Sbv += u[I] * (0.5f * (B[I] + B[(I)+1])); }
    DO_B(0) DO_B(1) DO_B(2) DO_B(3) DO_B(4)
    if (full) { DO_B(5) }   // guard: R[6]/G[6]/B[6] are garbage on lane 15
#undef DO_B

    Sr *= Tin; Sg *= Tin; Sbv *= Tin;
    RED(Sr) RED(Sg) RED(Sbv)
#undef RED

    // ---- stage outputs into this wave's OWN dead input slices ----
    // weights (380 floats) -> its D slice (384 floats)
    {
        float* wst = sh + SHD_OFF + w * 384 + rloc * 95 + 6 * l;
        float2* wst2 = (float2*)wst;
        wst2[0] = float2{Tin * u[0], Tin * u[1]};
        wst2[1] = float2{Tin * u[2], Tin * u[3]};
        if (full) wst2[2] = float2{Tin * u[4], Tin * u[5]};
        else      wst[4]  = Tin * u[4];
    }
    // rgb (12 floats) + depth (4 floats) -> its S slice
    if (l == 15) {
        float* cst = sh + SHS_OFF + w * 384;
        cst[rloc * 3 + 0] = 2.f * Sr  - 1.f;
        cst[rloc * 3 + 1] = 2.f * Sg  - 1.f;
        cst[rloc * 3 + 2] = 2.f * Sbv - 1.f;
        float dv = Sd / Sw;                    // normalize_depth
        float hi = 0.5f * (D[4] + D[5]);       // 0.5*(d[94]+d[95]) on lane 15
        dv = fmaxf(fminf(dv, hi), lo);         // NaN -> hi (ref: nan->inf->clip)
        cst[12 + rloc] = dv;
    }
    LGKM0;   // wave-local ds_writes visible to wave-local readback

    // ---- per-wave cooperative NT stores (all spans 16B-aligned) ----
    {
        // weights: 380 floats = 95 dwordx4 per wave
        const v4f* src = (const v4f*)(sh + SHD_OFF + w * 384);
        v4f* dst = (v4f*)(out + W_OFF + ((size_t)blk * RPB + 4 * w) * 95);
        __builtin_nontemporal_store(src[l64], dst + l64);
        if (l64 < 31) __builtin_nontemporal_store(src[64 + l64], dst + 64 + l64);
    }
    if (l64 < 3) {   // rgb: 12 floats = 3 dwordx4
        __builtin_nontemporal_store(
            ((const v4f*)(sh + SHS_OFF + w * 384))[l64],
            (v4f*)(out + RGB_OFF + ((size_t)blk * RPB + 4 * w) * 3) + l64);
    }
    if (l64 == 3) {  // depth: 4 floats = 1 dwordx4
        __builtin_nontemporal_store(
            ((const v4f*)(sh + SHS_OFF + w * 384 + 12))[0],
            (v4f*)(out + DEPTH_OFF + (size_t)blk * RPB + 4 * w));
    }
}

extern "C" void kernel_launch(void* const* d_in, const int* in_sizes, int n_in,
                              void* d_out, int out_size, void* d_ws, size_t ws_size,
                              hipStream_t stream) {
    const float* rgbs   = (const float*)d_in[0];
    const float* sigmas = (const float*)d_in[1];
    const float* depths = (const float*)d_in[2];
    float* out = (float*)d_out;

    // 16 rays per 256-thread block -> 4096 blocks, 5 blocks/CU resident
    integrate_kernel<<<NRAYS / RPB, 256, 0, stream>>>(rgbs, sigmas, depths, out);
}